// Round 4
// baseline (1336.526 us; speedup 1.0000x reference)
//
#include <hip/hip_runtime.h>
#include <math.h>

#define NN 50000
#define NPAD 50048            // 391 * 128
#define EE 800000
#define HH 4
#define DD 128
#define HDIM 512
#define LL 4

typedef __attribute__((ext_vector_type(8))) short short8;
typedef __attribute__((ext_vector_type(4))) float f32x4;

__device__ __forceinline__ float lk(float x, float s){ return x > 0.f ? x : s*x; }
__device__ __forceinline__ unsigned short f2bf(float f){
  unsigned u = __float_as_uint(f);
  u += 0x7FFFu + ((u >> 16) & 1u);
  return (unsigned short)(u >> 16);
}
__device__ __forceinline__ float lo16(unsigned u){ return __uint_as_float(u << 16); }
__device__ __forceinline__ float hi16(unsigned u){ return __uint_as_float(u & 0xFFFF0000u); }
__device__ __forceinline__ float bf2f(unsigned short u){ return __uint_as_float(((unsigned)u) << 16); }

// ---------------- CSR build ---------------------------------------------------------------------
__global__ void k_zero(int* p, int n){ int i = blockIdx.x*blockDim.x+threadIdx.x; if(i<n) p[i]=0; }

__global__ void k_hist(const int* __restrict__ dst, int* __restrict__ cnt){
  int e = blockIdx.x*blockDim.x+threadIdx.x;
  if (e < EE) atomicAdd(&cnt[dst[e]], 1);
}

__global__ __launch_bounds__(1024) void k_scan(const int* __restrict__ cnt, int* __restrict__ row_ptr){
  __shared__ int part[1024];
  int t = threadIdx.x;
  const int chunk = (NN + 1023)/1024;
  int b = t*chunk, e = b+chunk;
  if (b > NN) b = NN;
  if (e > NN) e = NN;
  int s = 0;
  for (int i=b;i<e;++i) s += cnt[i];
  part[t] = s;
  __syncthreads();
  for (int off=1; off<1024; off<<=1){
    int v = (t>=off) ? part[t-off] : 0;
    __syncthreads();
    part[t] += v;
    __syncthreads();
  }
  int run = part[t] - s;
  for (int i=b;i<e;++i){ row_ptr[i] = run; run += cnt[i]; }
  if (t==1023) row_ptr[NN] = part[1023];
}

__global__ void k_copy(const int* __restrict__ a, int* __restrict__ b, int n){
  int i = blockIdx.x*blockDim.x+threadIdx.x; if(i<n) b[i]=a[i];
}

__global__ void k_fill(const int* __restrict__ src, const int* __restrict__ dst,
                       int* __restrict__ cursor, int* __restrict__ csr_src){
  int e = blockIdx.x*blockDim.x+threadIdx.x;
  if (e >= EE) return;
  int d = dst[e];
  int p = atomicAdd(&cursor[d], 1);
  csr_src[p] = src[e];
}

// ---------------- weight transposes via LDS tiles (coalesced both sides) -----------------------
// W2t[l][n][k] = (n<512 ? W_fc[l][k][n] : W_res[l][k][n-512]);  grid (16, 2, 4), 256 thr
__global__ __launch_bounds__(256) void k_cvtw2(const float* __restrict__ Wf,
                                               const float* __restrict__ Wr,
                                               unsigned short* __restrict__ W2t){
  __shared__ float tile[64][65];
  int t = threadIdx.x;
  int n0 = blockIdx.x*64, k0 = blockIdx.y*64, l = blockIdx.z;
  const float* srcp = (n0 < 512) ? Wf : Wr;
  int nsrc = (n0 < 512) ? n0 : (n0 - 512);
  #pragma unroll
  for (int j=0;j<16;++j){
    int idx = t + j*256; int kk = idx>>6, nn = idx&63;
    tile[kk][nn] = srcp[(size_t)(l*128 + k0+kk)*512 + nsrc+nn];
  }
  __syncthreads();
  #pragma unroll
  for (int j=0;j<16;++j){
    int idx = t + j*256; int nn = idx>>6, kk = idx&63;
    W2t[((size_t)l*1024 + n0+nn)*128 + k0+kk] = f2bf(tile[kk][nn]);
  }
}
// Wnt[l][n][k] = W_nrm[l][k][n];  grid (2, 8, 4)
__global__ __launch_bounds__(256) void k_cvtwn(const float* __restrict__ Wn,
                                               unsigned short* __restrict__ Wnt){
  __shared__ float tile[64][65];
  int t = threadIdx.x;
  int n0 = blockIdx.x*64, k0 = blockIdx.y*64, l = blockIdx.z;
  #pragma unroll
  for (int j=0;j<16;++j){
    int idx = t + j*256; int kk = idx>>6, nn = idx&63;
    tile[kk][nn] = Wn[(size_t)(l*512 + k0+kk)*128 + n0+nn];
  }
  __syncthreads();
  #pragma unroll
  for (int j=0;j<16;++j){
    int idx = t + j*256; int nn = idx>>6, kk = idx&63;
    Wnt[((size_t)l*128 + n0+nn)*512 + k0+kk] = f2bf(tile[kk][nn]);
  }
}
// xb[NPAD,128] bf16 from features (pad rows = 0)
__global__ void k_cvtx(const float* __restrict__ x, unsigned short* __restrict__ xb){
  int idx = blockIdx.x*blockDim.x + threadIdx.x;
  int row = idx >> 7;
  xb[idx] = (row < NN) ? f2bf(x[idx]) : (unsigned short)0;
}

// ---------------- GEMM1 (MFMA) + fused el/er: [NPAD,128] @ W2t-block -> bf16, attn logits ------
__global__ __launch_bounds__(256) void k_gemm1m(const unsigned short* __restrict__ xb,
                                                const unsigned short* __restrict__ W2t,
                                                const float* __restrict__ al,
                                                const float* __restrict__ ar,
                                                unsigned short* __restrict__ featH,
                                                unsigned short* __restrict__ hbuf,
                                                float* __restrict__ elp,
                                                float* __restrict__ erp){
  __shared__ __attribute__((aligned(16))) char smem[2*128*136*2];
  __shared__ float sAl[128], sAr[128];
  unsigned short* sA = (unsigned short*)smem;
  unsigned short* sB = sA + 128*136;
  int t = threadIdx.x;
  int m0 = blockIdx.x*128;
  int n0 = blockIdx.y*128;
  int h = n0 >> 7;                               // head, valid when n0 < 512
  if (n0 < 512 && t < 128){ sAl[t] = al[h*128 + t]; sAr[t] = ar[h*128 + t]; }
  #pragma unroll
  for (int j=0;j<8;++j){
    int c = t + j*256; int r = c>>4, kc = c&15;
    uint4 v = *(const uint4*)(xb + (size_t)(m0+r)*128 + kc*8);
    *(uint4*)(sA + r*136 + kc*8) = v;
  }
  #pragma unroll
  for (int j=0;j<8;++j){
    int c = t + j*256; int r = c>>4, kc = c&15;
    uint4 v = *(const uint4*)(W2t + (size_t)(n0+r)*128 + kc*8);
    *(uint4*)(sB + r*136 + kc*8) = v;
  }
  __syncthreads();

  int lane = t & 63, w = t >> 6;
  int wm = (w & 1)*64, wn = (w >> 1)*64;
  int lrow = lane & 15, quad = lane >> 4;
  f32x4 acc[4][4];
  #pragma unroll
  for (int mt=0;mt<4;++mt)
    #pragma unroll
    for (int nt=0;nt<4;++nt) acc[mt][nt] = (f32x4){0.f,0.f,0.f,0.f};

  #pragma unroll
  for (int kq=0;kq<4;++kq){
    int kb = kq*32 + quad*8;
    short8 af[4], bf[4];
    #pragma unroll
    for (int mt=0;mt<4;++mt) af[mt] = *(const short8*)(sA + (wm+mt*16+lrow)*136 + kb);
    #pragma unroll
    for (int nt=0;nt<4;++nt) bf[nt] = *(const short8*)(sB + (wn+nt*16+lrow)*136 + kb);
    #pragma unroll
    for (int mt=0;mt<4;++mt)
      #pragma unroll
      for (int nt=0;nt<4;++nt)
        acc[mt][nt] = __builtin_amdgcn_mfma_f32_16x16x32_bf16(af[mt], bf[nt], acc[mt][nt], 0,0,0);
  }

  // repack bf16 tile through LDS
  __syncthreads();
  #pragma unroll
  for (int mt=0;mt<4;++mt)
    #pragma unroll
    for (int nt=0;nt<4;++nt)
      #pragma unroll
      for (int r=0;r<4;++r)
        sA[(wm+mt*16+quad*4+r)*136 + wn+nt*16+lrow] = f2bf(acc[mt][nt][r]);
  __syncthreads();
  unsigned short* dstB = (n0 < 512) ? (featH + (size_t)m0*512 + n0)
                                    : (hbuf  + (size_t)m0*512 + (n0-512));
  #pragma unroll
  for (int j=0;j<8;++j){
    int c = t + j*256; int r = c>>4, kc = c&15;
    uint4 v = *(const uint4*)(sA + r*136 + kc*8);
    *(uint4*)(dstB + (size_t)r*512 + kc*8) = v;
  }

  // fused attn logits for this head's 128 channels (2 threads per row)
  if (n0 < 512){
    int r = t >> 1, half = t & 1;
    int base = half*64;
    float accl = 0.f, accr = 0.f;
    #pragma unroll
    for (int d=0; d<64; d+=4){
      uint2 u = *(const uint2*)&sA[r*136 + base + d];
      float f0=lo16(u.x), f1=hi16(u.x), f2=lo16(u.y), f3=hi16(u.y);
      float4 a  = *(const float4*)&sAl[base+d];
      float4 rr = *(const float4*)&sAr[base+d];
      accl += f0*a.x + f1*a.y + f2*a.z + f3*a.w;
      accr += f0*rr.x + f1*rr.y + f2*rr.z + f3*rr.w;
    }
    accl += __shfl_xor(accl, 1);
    accr += __shfl_xor(accr, 1);
    if (half == 0 && (m0+r) < NN){
      elp[(size_t)(m0+r)*4 + h] = accl;
      erp[(size_t)(m0+r)*4 + h] = accr;
    }
  }
}

// ---------------- edge softmax + aggregation (XCD channel-split; h overwrites res) -------------
// grid = NN/2 blocks. blockIdx%8 in {0..3} -> channels 0..255, {4..7} -> 256..511, so each XCD
// (heuristic XCD = blockIdx%8) touches only half of each gathered row.
__global__ __launch_bounds__(256) void k_agg(const unsigned short* __restrict__ featH,
                                             unsigned short* __restrict__ hbuf,
                                             const float* __restrict__ el,
                                             const float* __restrict__ er,
                                             const int* __restrict__ row_ptr,
                                             const int* __restrict__ csr_src,
                                             const float* __restrict__ b_gat){
  int t = threadIdx.x;
  int lane = t & 63, w = t >> 6;
  int bid = blockIdx.x;
  int r8 = bid & 7, g = bid >> 3;
  int half = r8 >> 2, sub = r8 & 3;
  int node = g*16 + sub*4 + w;                   // covers [0, 50000) exactly
  int beg = row_ptr[node], end = row_ptr[node+1];
  float2 erv = *(const float2*)&er[(size_t)node*4 + 2*half];

  // pass 1: online softmax stats for this half's 2 heads
  float m0v=-1e30f, m1v=-1e30f, z0v=0.f, z1v=0.f;
  for (int i = beg + lane; i < end; i += 64){
    int s = csr_src[i];
    float2 ev = *(const float2*)&el[(size_t)s*4 + 2*half];
    float e0 = lk(ev.x+erv.x, 0.2f);
    float e1 = lk(ev.y+erv.y, 0.2f);
    if (e0 > m0v){ z0v = z0v*__expf(m0v-e0) + 1.f; m0v = e0; } else z0v += __expf(e0-m0v);
    if (e1 > m1v){ z1v = z1v*__expf(m1v-e1) + 1.f; m1v = e1; } else z1v += __expf(e1-m1v);
  }
  #pragma unroll
  for (int off=32; off>0; off>>=1){
    float mo = __shfl_xor(m0v, off), zo = __shfl_xor(z0v, off);
    float mn = fmaxf(m0v, mo);
    z0v = z0v*__expf(m0v-mn) + zo*__expf(mo-mn); m0v = mn;
    mo = __shfl_xor(m1v, off); zo = __shfl_xor(z1v, off);
    mn = fmaxf(m1v, mo);
    z1v = z1v*__expf(m1v-mn) + zo*__expf(mo-mn); m1v = mn;
  }
  float iz0 = 1.f / fmaxf(z0v, 1e-20f);
  float iz1 = 1.f / fmaxf(z1v, 1e-20f);

  // pass 2: lane owns channels half*256 + 4*lane .. +3 (local head hl = lane>>5)
  int hl = lane >> 5;
  float mh  = hl ? m1v : m0v;
  float izh = hl ? iz1 : iz0;
  float erh = hl ? erv.y : erv.x;
  const int eli = 2*half + hl;
  float acc0=0.f, acc1=0.f, acc2=0.f, acc3=0.f;
  for (int i = beg; i < end; ++i){
    int s = csr_src[i];
    float e = lk(el[(size_t)s*4 + eli] + erh, 0.2f);
    float wgt = __expf(e - mh) * izh;
    uint2 f = *(const uint2*)(featH + (size_t)s*HDIM + half*256 + 4*lane);
    acc0 += wgt*lo16(f.x); acc1 += wgt*hi16(f.x);
    acc2 += wgt*lo16(f.y); acc3 += wgt*hi16(f.y);
  }

  // epilogue: + residual + bias, leaky(0.01); overwrite res with h (bf16)
  uint2* rp = (uint2*)(hbuf + (size_t)node*HDIM + half*256 + 4*lane);
  uint2 rv = *rp;
  float4 bv = *(const float4*)(b_gat + half*256 + 4*lane);
  float o0 = lk(acc0+lo16(rv.x)+bv.x, 0.01f);
  float o1 = lk(acc1+hi16(rv.x)+bv.y, 0.01f);
  float o2 = lk(acc2+lo16(rv.y)+bv.z, 0.01f);
  float o3 = lk(acc3+hi16(rv.y)+bv.w, 0.01f);
  uint2 wv;
  wv.x = (unsigned)f2bf(o0) | ((unsigned)f2bf(o1) << 16);
  wv.y = (unsigned)f2bf(o2) | ((unsigned)f2bf(o3) << 16);
  *rp = wv;
}

// ---------------- GEMM3 (MFMA, K=512) + LayerNorm; writes bf16 xb and optional fp32 out --------
__global__ __launch_bounds__(256) void k_gemm3m(const unsigned short* __restrict__ h,
                                                const unsigned short* __restrict__ Wnt,
                                                const float* __restrict__ bn,
                                                const float* __restrict__ lng,
                                                const float* __restrict__ lnb,
                                                float* __restrict__ out,
                                                unsigned short* __restrict__ xb,
                                                int writeOut){
  __shared__ __attribute__((aligned(16))) char smem[2*128*136*2];
  unsigned short* sA = (unsigned short*)smem;
  unsigned short* sB = sA + 128*136;
  float* yf = (float*)smem;
  int t = threadIdx.x;
  int m0 = blockIdx.x*128;
  int lane = t & 63, w = t >> 6;
  int wm = (w & 1)*64, wn = (w >> 1)*64;
  int lrow = lane & 15, quad = lane >> 4;

  f32x4 acc[4][4];
  #pragma unroll
  for (int mt=0;mt<4;++mt)
    #pragma unroll
    for (int nt=0;nt<4;++nt) acc[mt][nt] = (f32x4){0.f,0.f,0.f,0.f};

  for (int kc2=0; kc2<4; ++kc2){
    if (kc2) __syncthreads();
    #pragma unroll
    for (int j=0;j<8;++j){
      int c = t + j*256; int r = c>>4, kc = c&15;
      uint4 v = *(const uint4*)(h + (size_t)(m0+r)*512 + kc2*128 + kc*8);
      *(uint4*)(sA + r*136 + kc*8) = v;
    }
    #pragma unroll
    for (int j=0;j<8;++j){
      int c = t + j*256; int r = c>>4, kc = c&15;
      uint4 v = *(const uint4*)(Wnt + (size_t)r*512 + kc2*128 + kc*8);
      *(uint4*)(sB + r*136 + kc*8) = v;
    }
    __syncthreads();
    #pragma unroll
    for (int kq=0;kq<4;++kq){
      int kb = kq*32 + quad*8;
      short8 af[4], bf[4];
      #pragma unroll
      for (int mt=0;mt<4;++mt) af[mt] = *(const short8*)(sA + (wm+mt*16+lrow)*136 + kb);
      #pragma unroll
      for (int nt=0;nt<4;++nt) bf[nt] = *(const short8*)(sB + (wn+nt*16+lrow)*136 + kb);
      #pragma unroll
      for (int mt=0;mt<4;++mt)
        #pragma unroll
        for (int nt=0;nt<4;++nt)
          acc[mt][nt] = __builtin_amdgcn_mfma_f32_16x16x32_bf16(af[mt], bf[nt], acc[mt][nt], 0,0,0);
    }
  }

  float bnv[4];
  #pragma unroll
  for (int nt=0;nt<4;++nt) bnv[nt] = bn[wn + nt*16 + lrow];
  __syncthreads();
  #pragma unroll
  for (int mt=0;mt<4;++mt)
    #pragma unroll
    for (int nt=0;nt<4;++nt)
      #pragma unroll
      for (int r=0;r<4;++r)
        yf[(wm+mt*16+quad*4+r)*132 + wn+nt*16+lrow] = acc[mt][nt][r] + bnv[nt];
  __syncthreads();

  float g0 = lng[lane], g1 = lng[64+lane];
  float bb0 = lnb[lane], bb1 = lnb[64+lane];
  for (int rr = w*32; rr < w*32+32; ++rr){
    float v0 = yf[rr*132 + lane], v1 = yf[rr*132 + 64 + lane];
    float s = v0 + v1;
    #pragma unroll
    for (int off=32; off>0; off>>=1) s += __shfl_xor(s, off);
    float mu = s * (1.f/128.f);
    float d0 = v0-mu, d1 = v1-mu;
    float q = d0*d0 + d1*d1;
    #pragma unroll
    for (int off=32; off>0; off>>=1) q += __shfl_xor(q, off);
    float inv = rsqrtf(q*(1.f/128.f) + 1e-5f);
    int grow = m0 + rr;
    if (grow < NN){
      float o0 = d0*inv*g0 + bb0;
      float o1 = d1*inv*g1 + bb1;
      xb[(size_t)grow*128 + lane]      = f2bf(o0);
      xb[(size_t)grow*128 + 64 + lane] = f2bf(o1);
      if (writeOut){
        out[(size_t)grow*128 + lane]      = o0;
        out[(size_t)grow*128 + 64 + lane] = o1;
      }
    }
  }
}

extern "C" void kernel_launch(void* const* d_in, const int* in_sizes, int n_in,
                              void* d_out, int out_size, void* d_ws, size_t ws_size,
                              hipStream_t stream){
  const float* features = (const float*)d_in[0];
  const int*   src      = (const int*)d_in[1];
  const int*   dst      = (const int*)d_in[2];
  const float* W_fc     = (const float*)d_in[3];
  const float* attn_l   = (const float*)d_in[4];
  const float* attn_r   = (const float*)d_in[5];
  const float* W_res    = (const float*)d_in[6];
  const float* b_gat    = (const float*)d_in[7];
  const float* W_nrm    = (const float*)d_in[8];
  const float* b_nrm    = (const float*)d_in[9];
  const float* ln_g     = (const float*)d_in[10];
  const float* ln_b     = (const float*)d_in[11];
  float* out = (float*)d_out;

  // workspace (~122 MB)
  unsigned short* xb    = (unsigned short*)d_ws;            // [NPAD,128] bf16
  unsigned short* featH = xb + (size_t)NPAD*128;            // [NPAD,512] bf16
  unsigned short* hbuf  = featH + (size_t)NPAD*512;         // [NPAD,512] bf16
  unsigned short* W2t   = hbuf + (size_t)NPAD*512;          // [L,1024,128] bf16
  unsigned short* Wnt   = W2t + (size_t)LL*1024*128;        // [L,128,512] bf16
  float* el = (float*)(Wnt + (size_t)LL*128*512);           // [N,4]
  float* er = el + (size_t)NN*4;                            // [N,4]
  int* row_ptr = (int*)(er + (size_t)NN*4);                 // N+1
  int* cursor  = row_ptr + (NN+1);                          // N
  int* csr_src = cursor + NN;                               // E

  // prep: weights + x0 + CSR
  k_cvtw2<<<dim3(16, 2, LL), 256, 0, stream>>>(W_fc, W_res, W2t);
  k_cvtwn<<<dim3(2, 8, LL), 256, 0, stream>>>(W_nrm, Wnt);
  k_cvtx<<<(NPAD*128)/256, 256, 0, stream>>>(features, xb);
  k_zero<<<(NN+255)/256, 256, 0, stream>>>(cursor, NN);
  k_hist<<<(EE+255)/256, 256, 0, stream>>>(dst, cursor);
  k_scan<<<1, 1024, 0, stream>>>(cursor, row_ptr);
  k_copy<<<(NN+255)/256, 256, 0, stream>>>(row_ptr, cursor, NN);
  k_fill<<<(EE+255)/256, 256, 0, stream>>>(src, dst, cursor, csr_src);

  for (int l=0; l<LL; ++l){
    const unsigned short* W2l = W2t + (size_t)l*1024*128;
    const unsigned short* Wnl = Wnt + (size_t)l*128*512;
    const float* al = attn_l + (size_t)l*HH*DD;
    const float* ar = attn_r + (size_t)l*HH*DD;
    const float* bg = b_gat  + (size_t)l*HDIM;
    const float* bn = b_nrm  + (size_t)l*DD;
    const float* lg = ln_g   + (size_t)l*DD;
    const float* lb = ln_b   + (size_t)l*DD;

    k_gemm1m<<<dim3(NPAD/128, 8), 256, 0, stream>>>(xb, W2l, al, ar, featH, hbuf, el, er);
    k_agg<<<NN/2, 256, 0, stream>>>(featH, hbuf, el, er, row_ptr, csr_src, bg);
    k_gemm3m<<<NPAD/128, 256, 0, stream>>>(hbuf, Wnl, bn, lg, lb, out, xb, (l==LL-1) ? 1 : 0);
  }
}

// Round 5
// 1081.489 us; speedup vs baseline: 1.2358x; 1.2358x over previous
//
#include <hip/hip_runtime.h>
#include <math.h>

#define NN 50000
#define NPAD 50048            // 391 * 128
#define EE 800000
#define HH 4
#define DD 128
#define HDIM 512
#define LL 4

typedef __attribute__((ext_vector_type(8))) short short8;
typedef __attribute__((ext_vector_type(4))) float f32x4;

__device__ __forceinline__ float lk(float x, float s){ return x > 0.f ? x : s*x; }
__device__ __forceinline__ unsigned short f2bf(float f){
  unsigned u = __float_as_uint(f);
  u += 0x7FFFu + ((u >> 16) & 1u);
  return (unsigned short)(u >> 16);
}
__device__ __forceinline__ float lo16(unsigned u){ return __uint_as_float(u << 16); }
__device__ __forceinline__ float hi16(unsigned u){ return __uint_as_float(u & 0xFFFF0000u); }

// ---------------- CSR build ---------------------------------------------------------------------
__global__ void k_zero(int* p, int n){ int i = blockIdx.x*blockDim.x+threadIdx.x; if(i<n) p[i]=0; }

__global__ void k_hist(const int* __restrict__ dst, int* __restrict__ cnt){
  int e = blockIdx.x*blockDim.x+threadIdx.x;
  if (e < EE) atomicAdd(&cnt[dst[e]], 1);
}

__global__ __launch_bounds__(1024) void k_scan(const int* __restrict__ cnt, int* __restrict__ row_ptr){
  __shared__ int part[1024];
  int t = threadIdx.x;
  const int chunk = (NN + 1023)/1024;
  int b = t*chunk, e = b+chunk;
  if (b > NN) b = NN;
  if (e > NN) e = NN;
  int s = 0;
  for (int i=b;i<e;++i) s += cnt[i];
  part[t] = s;
  __syncthreads();
  for (int off=1; off<1024; off<<=1){
    int v = (t>=off) ? part[t-off] : 0;
    __syncthreads();
    part[t] += v;
    __syncthreads();
  }
  int run = part[t] - s;
  for (int i=b;i<e;++i){ row_ptr[i] = run; run += cnt[i]; }
  if (t==1023) row_ptr[NN] = part[1023];
}

__global__ void k_copy(const int* __restrict__ a, int* __restrict__ b, int n){
  int i = blockIdx.x*blockDim.x+threadIdx.x; if(i<n) b[i]=a[i];
}

__global__ void k_fill(const int* __restrict__ src, const int* __restrict__ dst,
                       int* __restrict__ cursor, int* __restrict__ csr_src){
  int e = blockIdx.x*blockDim.x+threadIdx.x;
  if (e >= EE) return;
  int d = dst[e];
  int p = atomicAdd(&cursor[d], 1);
  csr_src[p] = src[e];
}

// ---------------- weight transposes via LDS tiles (coalesced both sides) -----------------------
__global__ __launch_bounds__(256) void k_cvtw2(const float* __restrict__ Wf,
                                               const float* __restrict__ Wr,
                                               unsigned short* __restrict__ W2t){
  __shared__ float tile[64][65];
  int t = threadIdx.x;
  int n0 = blockIdx.x*64, k0 = blockIdx.y*64, l = blockIdx.z;
  const float* srcp = (n0 < 512) ? Wf : Wr;
  int nsrc = (n0 < 512) ? n0 : (n0 - 512);
  #pragma unroll
  for (int j=0;j<16;++j){
    int idx = t + j*256; int kk = idx>>6, nn = idx&63;
    tile[kk][nn] = srcp[(size_t)(l*128 + k0+kk)*512 + nsrc+nn];
  }
  __syncthreads();
  #pragma unroll
  for (int j=0;j<16;++j){
    int idx = t + j*256; int nn = idx>>6, kk = idx&63;
    W2t[((size_t)l*1024 + n0+nn)*128 + k0+kk] = f2bf(tile[kk][nn]);
  }
}
__global__ __launch_bounds__(256) void k_cvtwn(const float* __restrict__ Wn,
                                               unsigned short* __restrict__ Wnt){
  __shared__ float tile[64][65];
  int t = threadIdx.x;
  int n0 = blockIdx.x*64, k0 = blockIdx.y*64, l = blockIdx.z;
  #pragma unroll
  for (int j=0;j<16;++j){
    int idx = t + j*256; int kk = idx>>6, nn = idx&63;
    tile[kk][nn] = Wn[(size_t)(l*512 + k0+kk)*128 + n0+nn];
  }
  __syncthreads();
  #pragma unroll
  for (int j=0;j<16;++j){
    int idx = t + j*256; int nn = idx>>6, kk = idx&63;
    Wnt[((size_t)l*128 + n0+nn)*512 + k0+kk] = f2bf(tile[kk][nn]);
  }
}
__global__ void k_cvtx(const float* __restrict__ x, unsigned short* __restrict__ xb){
  int idx = blockIdx.x*blockDim.x + threadIdx.x;
  int row = idx >> 7;
  xb[idx] = (row < NN) ? f2bf(x[idx]) : (unsigned short)0;
}

// ---------------- GEMM1 (MFMA) + fused el/er logits --------------------------------------------
__global__ __launch_bounds__(256) void k_gemm1m(const unsigned short* __restrict__ xb,
                                                const unsigned short* __restrict__ W2t,
                                                const float* __restrict__ al,
                                                const float* __restrict__ ar,
                                                unsigned short* __restrict__ featH,
                                                unsigned short* __restrict__ hbuf,
                                                float* __restrict__ elp,
                                                float* __restrict__ erp){
  __shared__ __attribute__((aligned(16))) char smem[2*128*136*2];
  __shared__ float sAl[128], sAr[128];
  unsigned short* sA = (unsigned short*)smem;
  unsigned short* sB = sA + 128*136;
  int t = threadIdx.x;
  int m0 = blockIdx.x*128;
  int n0 = blockIdx.y*128;
  int h = n0 >> 7;
  if (n0 < 512 && t < 128){ sAl[t] = al[h*128 + t]; sAr[t] = ar[h*128 + t]; }
  #pragma unroll
  for (int j=0;j<8;++j){
    int c = t + j*256; int r = c>>4, kc = c&15;
    uint4 v = *(const uint4*)(xb + (size_t)(m0+r)*128 + kc*8);
    *(uint4*)(sA + r*136 + kc*8) = v;
  }
  #pragma unroll
  for (int j=0;j<8;++j){
    int c = t + j*256; int r = c>>4, kc = c&15;
    uint4 v = *(const uint4*)(W2t + (size_t)(n0+r)*128 + kc*8);
    *(uint4*)(sB + r*136 + kc*8) = v;
  }
  __syncthreads();

  int lane = t & 63, w = t >> 6;
  int wm = (w & 1)*64, wn = (w >> 1)*64;
  int lrow = lane & 15, quad = lane >> 4;
  f32x4 acc[4][4];
  #pragma unroll
  for (int mt=0;mt<4;++mt)
    #pragma unroll
    for (int nt=0;nt<4;++nt) acc[mt][nt] = (f32x4){0.f,0.f,0.f,0.f};

  #pragma unroll
  for (int kq=0;kq<4;++kq){
    int kb = kq*32 + quad*8;
    short8 af[4], bf[4];
    #pragma unroll
    for (int mt=0;mt<4;++mt) af[mt] = *(const short8*)(sA + (wm+mt*16+lrow)*136 + kb);
    #pragma unroll
    for (int nt=0;nt<4;++nt) bf[nt] = *(const short8*)(sB + (wn+nt*16+lrow)*136 + kb);
    #pragma unroll
    for (int mt=0;mt<4;++mt)
      #pragma unroll
      for (int nt=0;nt<4;++nt)
        acc[mt][nt] = __builtin_amdgcn_mfma_f32_16x16x32_bf16(af[mt], bf[nt], acc[mt][nt], 0,0,0);
  }

  __syncthreads();
  #pragma unroll
  for (int mt=0;mt<4;++mt)
    #pragma unroll
    for (int nt=0;nt<4;++nt)
      #pragma unroll
      for (int r=0;r<4;++r)
        sA[(wm+mt*16+quad*4+r)*136 + wn+nt*16+lrow] = f2bf(acc[mt][nt][r]);
  __syncthreads();
  unsigned short* dstB = (n0 < 512) ? (featH + (size_t)m0*512 + n0)
                                    : (hbuf  + (size_t)m0*512 + (n0-512));
  #pragma unroll
  for (int j=0;j<8;++j){
    int c = t + j*256; int r = c>>4, kc = c&15;
    uint4 v = *(const uint4*)(sA + r*136 + kc*8);
    *(uint4*)(dstB + (size_t)r*512 + kc*8) = v;
  }

  if (n0 < 512){
    int r = t >> 1, half = t & 1;
    int base = half*64;
    float accl = 0.f, accr = 0.f;
    #pragma unroll
    for (int d=0; d<64; d+=4){
      uint2 u = *(const uint2*)&sA[r*136 + base + d];
      float f0=lo16(u.x), f1=hi16(u.x), f2=lo16(u.y), f3=hi16(u.y);
      float4 a  = *(const float4*)&sAl[base+d];
      float4 rr = *(const float4*)&sAr[base+d];
      accl += f0*a.x + f1*a.y + f2*a.z + f3*a.w;
      accr += f0*rr.x + f1*rr.y + f2*rr.z + f3*rr.w;
    }
    accl += __shfl_xor(accl, 1);
    accr += __shfl_xor(accr, 1);
    if (half == 0 && (m0+r) < NN){
      elp[(size_t)(m0+r)*4 + h] = accl;
      erp[(size_t)(m0+r)*4 + h] = accr;
    }
  }
}

// ---------------- edge softmax + aggregation: SINGLE PASS, one wave per node -------------------
// exp(e) is bounded here (|el+er| <~ 3), so softmax needs no max-subtraction:
// acc += exp(e)*feat ; z += exp(e) ; scale by 1/z at the end. One feat gather per edge.
__global__ __launch_bounds__(256) void k_agg(const unsigned short* __restrict__ featH,
                                             unsigned short* __restrict__ hbuf,
                                             const float* __restrict__ el,
                                             const float* __restrict__ er,
                                             const int* __restrict__ row_ptr,
                                             const int* __restrict__ csr_src,
                                             const float* __restrict__ b_gat){
  int t = threadIdx.x;
  int lane = t & 63;
  int node = blockIdx.x*4 + (t>>6);              // NN % 4 == 0, grid exact
  int beg = row_ptr[node], end = row_ptr[node+1];
  float4 erv = *(const float4*)&er[(size_t)node*4];

  // lane owns channels [4*lane..+3] (head lane>>5) and [256+4*lane..+3] (head 2+(lane>>5))
  int hsel = lane >> 5;
  float er1 = hsel ? erv.y : erv.x;
  float er2 = hsel ? erv.w : erv.z;
  float z1 = 0.f, z2 = 0.f;
  float acc[8] = {0.f,0.f,0.f,0.f,0.f,0.f,0.f,0.f};
  for (int i = beg; i < end; ++i){
    int s = csr_src[i];
    float4 ev = *(const float4*)&el[(size_t)s*4];   // broadcast (wave-uniform address)
    float e1 = lk((hsel ? ev.y : ev.x) + er1, 0.2f);
    float e2 = lk((hsel ? ev.w : ev.z) + er2, 0.2f);
    float w1 = __expf(e1);
    float w2 = __expf(e2);
    z1 += w1; z2 += w2;
    const uint2* fp = (const uint2*)(featH + (size_t)s*HDIM);
    uint2 fa = fp[lane];
    uint2 fb = fp[64 + lane];
    acc[0] += w1*lo16(fa.x); acc[1] += w1*hi16(fa.x);
    acc[2] += w1*lo16(fa.y); acc[3] += w1*hi16(fa.y);
    acc[4] += w2*lo16(fb.x); acc[5] += w2*hi16(fb.x);
    acc[6] += w2*lo16(fb.y); acc[7] += w2*hi16(fb.y);
  }
  float iz1 = 1.f / fmaxf(z1, 1e-20f);
  float iz2 = 1.f / fmaxf(z2, 1e-20f);

  uint2* rp = (uint2*)(hbuf + (size_t)node*HDIM);
  uint2 r1 = rp[lane], r2 = rp[64+lane];
  const float4* bp = (const float4*)b_gat;
  float4 b1 = bp[lane], b2 = bp[64+lane];
  float o0 = lk(acc[0]*iz1+lo16(r1.x)+b1.x, 0.01f);
  float o1 = lk(acc[1]*iz1+hi16(r1.x)+b1.y, 0.01f);
  float o2 = lk(acc[2]*iz1+lo16(r1.y)+b1.z, 0.01f);
  float o3 = lk(acc[3]*iz1+hi16(r1.y)+b1.w, 0.01f);
  float o4 = lk(acc[4]*iz2+lo16(r2.x)+b2.x, 0.01f);
  float o5 = lk(acc[5]*iz2+hi16(r2.x)+b2.y, 0.01f);
  float o6 = lk(acc[6]*iz2+lo16(r2.y)+b2.z, 0.01f);
  float o7 = lk(acc[7]*iz2+hi16(r2.y)+b2.w, 0.01f);
  uint2 w1v, w2v;
  w1v.x = (unsigned)f2bf(o0) | ((unsigned)f2bf(o1) << 16);
  w1v.y = (unsigned)f2bf(o2) | ((unsigned)f2bf(o3) << 16);
  w2v.x = (unsigned)f2bf(o4) | ((unsigned)f2bf(o5) << 16);
  w2v.y = (unsigned)f2bf(o6) | ((unsigned)f2bf(o7) << 16);
  rp[lane] = w1v; rp[64+lane] = w2v;
}

// ---------------- GEMM3 (MFMA, K=512) + LayerNorm ----------------------------------------------
__global__ __launch_bounds__(256) void k_gemm3m(const unsigned short* __restrict__ h,
                                                const unsigned short* __restrict__ Wnt,
                                                const float* __restrict__ bn,
                                                const float* __restrict__ lng,
                                                const float* __restrict__ lnb,
                                                float* __restrict__ out,
                                                unsigned short* __restrict__ xb,
                                                int writeOut){
  __shared__ __attribute__((aligned(16))) char smem[2*128*136*2];
  unsigned short* sA = (unsigned short*)smem;
  unsigned short* sB = sA + 128*136;
  float* yf = (float*)smem;
  int t = threadIdx.x;
  int m0 = blockIdx.x*128;
  int lane = t & 63, w = t >> 6;
  int wm = (w & 1)*64, wn = (w >> 1)*64;
  int lrow = lane & 15, quad = lane >> 4;

  f32x4 acc[4][4];
  #pragma unroll
  for (int mt=0;mt<4;++mt)
    #pragma unroll
    for (int nt=0;nt<4;++nt) acc[mt][nt] = (f32x4){0.f,0.f,0.f,0.f};

  for (int kc2=0; kc2<4; ++kc2){
    if (kc2) __syncthreads();
    #pragma unroll
    for (int j=0;j<8;++j){
      int c = t + j*256; int r = c>>4, kc = c&15;
      uint4 v = *(const uint4*)(h + (size_t)(m0+r)*512 + kc2*128 + kc*8);
      *(uint4*)(sA + r*136 + kc*8) = v;
    }
    #pragma unroll
    for (int j=0;j<8;++j){
      int c = t + j*256; int r = c>>4, kc = c&15;
      uint4 v = *(const uint4*)(Wnt + (size_t)r*512 + kc2*128 + kc*8);
      *(uint4*)(sB + r*136 + kc*8) = v;
    }
    __syncthreads();
    #pragma unroll
    for (int kq=0;kq<4;++kq){
      int kb = kq*32 + quad*8;
      short8 af[4], bf[4];
      #pragma unroll
      for (int mt=0;mt<4;++mt) af[mt] = *(const short8*)(sA + (wm+mt*16+lrow)*136 + kb);
      #pragma unroll
      for (int nt=0;nt<4;++nt) bf[nt] = *(const short8*)(sB + (wn+nt*16+lrow)*136 + kb);
      #pragma unroll
      for (int mt=0;mt<4;++mt)
        #pragma unroll
        for (int nt=0;nt<4;++nt)
          acc[mt][nt] = __builtin_amdgcn_mfma_f32_16x16x32_bf16(af[mt], bf[nt], acc[mt][nt], 0,0,0);
    }
  }

  float bnv[4];
  #pragma unroll
  for (int nt=0;nt<4;++nt) bnv[nt] = bn[wn + nt*16 + lrow];
  __syncthreads();
  #pragma unroll
  for (int mt=0;mt<4;++mt)
    #pragma unroll
    for (int nt=0;nt<4;++nt)
      #pragma unroll
      for (int r=0;r<4;++r)
        yf[(wm+mt*16+quad*4+r)*132 + wn+nt*16+lrow] = acc[mt][nt][r] + bnv[nt];
  __syncthreads();

  float g0 = lng[lane], g1 = lng[64+lane];
  float bb0 = lnb[lane], bb1 = lnb[64+lane];
  for (int rr = w*32; rr < w*32+32; ++rr){
    float v0 = yf[rr*132 + lane], v1 = yf[rr*132 + 64 + lane];
    float s = v0 + v1;
    #pragma unroll
    for (int off=32; off>0; off>>=1) s += __shfl_xor(s, off);
    float mu = s * (1.f/128.f);
    float d0 = v0-mu, d1 = v1-mu;
    float q = d0*d0 + d1*d1;
    #pragma unroll
    for (int off=32; off>0; off>>=1) q += __shfl_xor(q, off);
    float inv = rsqrtf(q*(1.f/128.f) + 1e-5f);
    int grow = m0 + rr;
    if (grow < NN){
      float o0 = d0*inv*g0 + bb0;
      float o1 = d1*inv*g1 + bb1;
      xb[(size_t)grow*128 + lane]      = f2bf(o0);
      xb[(size_t)grow*128 + 64 + lane] = f2bf(o1);
      if (writeOut){
        out[(size_t)grow*128 + lane]      = o0;
        out[(size_t)grow*128 + 64 + lane] = o1;
      }
    }
  }
}

extern "C" void kernel_launch(void* const* d_in, const int* in_sizes, int n_in,
                              void* d_out, int out_size, void* d_ws, size_t ws_size,
                              hipStream_t stream){
  const float* features = (const float*)d_in[0];
  const int*   src      = (const int*)d_in[1];
  const int*   dst      = (const int*)d_in[2];
  const float* W_fc     = (const float*)d_in[3];
  const float* attn_l   = (const float*)d_in[4];
  const float* attn_r   = (const float*)d_in[5];
  const float* W_res    = (const float*)d_in[6];
  const float* b_gat    = (const float*)d_in[7];
  const float* W_nrm    = (const float*)d_in[8];
  const float* b_nrm    = (const float*)d_in[9];
  const float* ln_g     = (const float*)d_in[10];
  const float* ln_b     = (const float*)d_in[11];
  float* out = (float*)d_out;

  // workspace (~122 MB)
  unsigned short* xb    = (unsigned short*)d_ws;            // [NPAD,128] bf16
  unsigned short* featH = xb + (size_t)NPAD*128;            // [NPAD,512] bf16
  unsigned short* hbuf  = featH + (size_t)NPAD*512;         // [NPAD,512] bf16
  unsigned short* W2t   = hbuf + (size_t)NPAD*512;          // [L,1024,128] bf16
  unsigned short* Wnt   = W2t + (size_t)LL*1024*128;        // [L,128,512] bf16
  float* el = (float*)(Wnt + (size_t)LL*128*512);           // [N,4]
  float* er = el + (size_t)NN*4;                            // [N,4]
  int* row_ptr = (int*)(er + (size_t)NN*4);                 // N+1
  int* cursor  = row_ptr + (NN+1);                          // N
  int* csr_src = cursor + NN;                               // E

  k_cvtw2<<<dim3(16, 2, LL), 256, 0, stream>>>(W_fc, W_res, W2t);
  k_cvtwn<<<dim3(2, 8, LL), 256, 0, stream>>>(W_nrm, Wnt);
  k_cvtx<<<(NPAD*128)/256, 256, 0, stream>>>(features, xb);
  k_zero<<<(NN+255)/256, 256, 0, stream>>>(cursor, NN);
  k_hist<<<(EE+255)/256, 256, 0, stream>>>(dst, cursor);
  k_scan<<<1, 1024, 0, stream>>>(cursor, row_ptr);
  k_copy<<<(NN+255)/256, 256, 0, stream>>>(row_ptr, cursor, NN);
  k_fill<<<(EE+255)/256, 256, 0, stream>>>(src, dst, cursor, csr_src);

  for (int l=0; l<LL; ++l){
    const unsigned short* W2l = W2t + (size_t)l*1024*128;
    const unsigned short* Wnl = Wnt + (size_t)l*128*512;
    const float* al = attn_l + (size_t)l*HH*DD;
    const float* ar = attn_r + (size_t)l*HH*DD;
    const float* bg = b_gat  + (size_t)l*HDIM;
    const float* bn = b_nrm  + (size_t)l*DD;
    const float* lg = ln_g   + (size_t)l*DD;
    const float* lb = ln_b   + (size_t)l*DD;

    k_gemm1m<<<dim3(NPAD/128, 8), 256, 0, stream>>>(xb, W2l, al, ar, featH, hbuf, el, er);
    k_agg<<<NN/4, 256, 0, stream>>>(featH, hbuf, el, er, row_ptr, csr_src, bg);
    k_gemm3m<<<NPAD/128, 256, 0, stream>>>(hbuf, Wnl, bn, lg, lb, out, xb, (l==LL-1) ? 1 : 0);
  }
}

// Round 6
// 1057.391 us; speedup vs baseline: 1.2640x; 1.0228x over previous
//
#include <hip/hip_runtime.h>
#include <math.h>

#define NN 50000
#define NPAD 50048            // 391 * 128
#define EE 800000
#define HH 4
#define DD 128
#define HDIM 512
#define LL 4

typedef __attribute__((ext_vector_type(8))) short short8;
typedef __attribute__((ext_vector_type(4))) float f32x4;

__device__ __forceinline__ float lk(float x, float s){ return x > 0.f ? x : s*x; }
__device__ __forceinline__ unsigned short f2bf(float f){
  unsigned u = __float_as_uint(f);
  u += 0x7FFFu + ((u >> 16) & 1u);
  return (unsigned short)(u >> 16);
}
__device__ __forceinline__ float lo16(unsigned u){ return __uint_as_float(u << 16); }
__device__ __forceinline__ float hi16(unsigned u){ return __uint_as_float(u & 0xFFFF0000u); }

// ---------------- CSR build ---------------------------------------------------------------------
__global__ void k_zero(int* p, int n){ int i = blockIdx.x*blockDim.x+threadIdx.x; if(i<n) p[i]=0; }

__global__ void k_hist(const int* __restrict__ dst, int* __restrict__ cnt){
  int e = blockIdx.x*blockDim.x+threadIdx.x;
  if (e < EE) atomicAdd(&cnt[dst[e]], 1);
}

__global__ __launch_bounds__(1024) void k_scan(const int* __restrict__ cnt, int* __restrict__ row_ptr){
  __shared__ int part[1024];
  int t = threadIdx.x;
  const int chunk = (NN + 1023)/1024;
  int b = t*chunk, e = b+chunk;
  if (b > NN) b = NN;
  if (e > NN) e = NN;
  int s = 0;
  for (int i=b;i<e;++i) s += cnt[i];
  part[t] = s;
  __syncthreads();
  for (int off=1; off<1024; off<<=1){
    int v = (t>=off) ? part[t-off] : 0;
    __syncthreads();
    part[t] += v;
    __syncthreads();
  }
  int run = part[t] - s;
  for (int i=b;i<e;++i){ row_ptr[i] = run; run += cnt[i]; }
  if (t==1023) row_ptr[NN] = part[1023];
}

__global__ void k_copy(const int* __restrict__ a, int* __restrict__ b, int n){
  int i = blockIdx.x*blockDim.x+threadIdx.x; if(i<n) b[i]=a[i];
}

__global__ void k_fill(const int* __restrict__ src, const int* __restrict__ dst,
                       int* __restrict__ cursor, int* __restrict__ csr_src){
  int e = blockIdx.x*blockDim.x+threadIdx.x;
  if (e >= EE) return;
  int d = dst[e];
  int p = atomicAdd(&cursor[d], 1);
  csr_src[p] = src[e];
}

// ---------------- weight transposes via LDS tiles (coalesced both sides) -----------------------
__global__ __launch_bounds__(256) void k_cvtw2(const float* __restrict__ Wf,
                                               const float* __restrict__ Wr,
                                               unsigned short* __restrict__ W2t){
  __shared__ float tile[64][65];
  int t = threadIdx.x;
  int n0 = blockIdx.x*64, k0 = blockIdx.y*64, l = blockIdx.z;
  const float* srcp = (n0 < 512) ? Wf : Wr;
  int nsrc = (n0 < 512) ? n0 : (n0 - 512);
  #pragma unroll
  for (int j=0;j<16;++j){
    int idx = t + j*256; int kk = idx>>6, nn = idx&63;
    tile[kk][nn] = srcp[(size_t)(l*128 + k0+kk)*512 + nsrc+nn];
  }
  __syncthreads();
  #pragma unroll
  for (int j=0;j<16;++j){
    int idx = t + j*256; int nn = idx>>6, kk = idx&63;
    W2t[((size_t)l*1024 + n0+nn)*128 + k0+kk] = f2bf(tile[kk][nn]);
  }
}
__global__ __launch_bounds__(256) void k_cvtwn(const float* __restrict__ Wn,
                                               unsigned short* __restrict__ Wnt){
  __shared__ float tile[64][65];
  int t = threadIdx.x;
  int n0 = blockIdx.x*64, k0 = blockIdx.y*64, l = blockIdx.z;
  #pragma unroll
  for (int j=0;j<16;++j){
    int idx = t + j*256; int kk = idx>>6, nn = idx&63;
    tile[kk][nn] = Wn[(size_t)(l*512 + k0+kk)*128 + n0+nn];
  }
  __syncthreads();
  #pragma unroll
  for (int j=0;j<16;++j){
    int idx = t + j*256; int nn = idx>>6, kk = idx&63;
    Wnt[((size_t)l*128 + n0+nn)*512 + k0+kk] = f2bf(tile[kk][nn]);
  }
}
__global__ void k_cvtx(const float* __restrict__ x, unsigned short* __restrict__ xb){
  int idx = blockIdx.x*blockDim.x + threadIdx.x;
  int row = idx >> 7;
  xb[idx] = (row < NN) ? f2bf(x[idx]) : (unsigned short)0;
}

// ---------------- GEMM1 (MFMA) + fused el/er logits --------------------------------------------
__global__ __launch_bounds__(256) void k_gemm1m(const unsigned short* __restrict__ xb,
                                                const unsigned short* __restrict__ W2t,
                                                const float* __restrict__ al,
                                                const float* __restrict__ ar,
                                                unsigned short* __restrict__ featH,
                                                unsigned short* __restrict__ hbuf,
                                                float* __restrict__ elp,
                                                float* __restrict__ erp){
  __shared__ __attribute__((aligned(16))) char smem[2*128*136*2];
  __shared__ float sAl[128], sAr[128];
  unsigned short* sA = (unsigned short*)smem;
  unsigned short* sB = sA + 128*136;
  int t = threadIdx.x;
  int m0 = blockIdx.x*128;
  int n0 = blockIdx.y*128;
  int h = n0 >> 7;
  if (n0 < 512 && t < 128){ sAl[t] = al[h*128 + t]; sAr[t] = ar[h*128 + t]; }
  #pragma unroll
  for (int j=0;j<8;++j){
    int c = t + j*256; int r = c>>4, kc = c&15;
    uint4 v = *(const uint4*)(xb + (size_t)(m0+r)*128 + kc*8);
    *(uint4*)(sA + r*136 + kc*8) = v;
  }
  #pragma unroll
  for (int j=0;j<8;++j){
    int c = t + j*256; int r = c>>4, kc = c&15;
    uint4 v = *(const uint4*)(W2t + (size_t)(n0+r)*128 + kc*8);
    *(uint4*)(sB + r*136 + kc*8) = v;
  }
  __syncthreads();

  int lane = t & 63, w = t >> 6;
  int wm = (w & 1)*64, wn = (w >> 1)*64;
  int lrow = lane & 15, quad = lane >> 4;
  f32x4 acc[4][4];
  #pragma unroll
  for (int mt=0;mt<4;++mt)
    #pragma unroll
    for (int nt=0;nt<4;++nt) acc[mt][nt] = (f32x4){0.f,0.f,0.f,0.f};

  #pragma unroll
  for (int kq=0;kq<4;++kq){
    int kb = kq*32 + quad*8;
    short8 af[4], bf[4];
    #pragma unroll
    for (int mt=0;mt<4;++mt) af[mt] = *(const short8*)(sA + (wm+mt*16+lrow)*136 + kb);
    #pragma unroll
    for (int nt=0;nt<4;++nt) bf[nt] = *(const short8*)(sB + (wn+nt*16+lrow)*136 + kb);
    #pragma unroll
    for (int mt=0;mt<4;++mt)
      #pragma unroll
      for (int nt=0;nt<4;++nt)
        acc[mt][nt] = __builtin_amdgcn_mfma_f32_16x16x32_bf16(af[mt], bf[nt], acc[mt][nt], 0,0,0);
  }

  __syncthreads();
  #pragma unroll
  for (int mt=0;mt<4;++mt)
    #pragma unroll
    for (int nt=0;nt<4;++nt)
      #pragma unroll
      for (int r=0;r<4;++r)
        sA[(wm+mt*16+quad*4+r)*136 + wn+nt*16+lrow] = f2bf(acc[mt][nt][r]);
  __syncthreads();
  unsigned short* dstB = (n0 < 512) ? (featH + (size_t)m0*512 + n0)
                                    : (hbuf  + (size_t)m0*512 + (n0-512));
  #pragma unroll
  for (int j=0;j<8;++j){
    int c = t + j*256; int r = c>>4, kc = c&15;
    uint4 v = *(const uint4*)(sA + r*136 + kc*8);
    *(uint4*)(dstB + (size_t)r*512 + kc*8) = v;
  }

  if (n0 < 512){
    int r = t >> 1, half = t & 1;
    int base = half*64;
    float accl = 0.f, accr = 0.f;
    #pragma unroll
    for (int d=0; d<64; d+=4){
      uint2 u = *(const uint2*)&sA[r*136 + base + d];
      float f0=lo16(u.x), f1=hi16(u.x), f2=lo16(u.y), f3=hi16(u.y);
      float4 a  = *(const float4*)&sAl[base+d];
      float4 rr = *(const float4*)&sAr[base+d];
      accl += f0*a.x + f1*a.y + f2*a.z + f3*a.w;
      accr += f0*rr.x + f1*rr.y + f2*rr.z + f3*rr.w;
    }
    accl += __shfl_xor(accl, 1);
    accr += __shfl_xor(accr, 1);
    if (half == 0 && (m0+r) < NN){
      elp[(size_t)(m0+r)*4 + h] = accl;
      erp[(size_t)(m0+r)*4 + h] = accr;
    }
  }
}

// ---------------- edge softmax + aggregation: single pass, 4x unrolled gather ------------------
// No max-subtraction needed (|el+er| bounded ~3 -> exp safe). 4 edges in flight: 4 idx + 4 el +
// 8 feat loads issued before any use, to hide random-gather latency.
__global__ __launch_bounds__(256) void k_agg(const unsigned short* __restrict__ featH,
                                             unsigned short* __restrict__ hbuf,
                                             const float* __restrict__ el,
                                             const float* __restrict__ er,
                                             const int* __restrict__ row_ptr,
                                             const int* __restrict__ csr_src,
                                             const float* __restrict__ b_gat){
  int t = threadIdx.x;
  int lane = t & 63;
  int node = blockIdx.x*4 + (t>>6);              // NN % 4 == 0, grid exact
  int beg = row_ptr[node], end = row_ptr[node+1];
  float4 erv = *(const float4*)&er[(size_t)node*4];

  int hsel = lane >> 5;
  float er1 = hsel ? erv.y : erv.x;
  float er2 = hsel ? erv.w : erv.z;
  float z1 = 0.f, z2 = 0.f;
  float acc[8] = {0.f,0.f,0.f,0.f,0.f,0.f,0.f,0.f};
  const uint2* fH = (const uint2*)featH;         // row = 128 uint2

  int i = beg;
  for (; i + 3 < end; i += 4){
    int s0 = csr_src[i], s1 = csr_src[i+1], s2 = csr_src[i+2], s3 = csr_src[i+3];
    float4 ev0 = *(const float4*)&el[(size_t)s0*4];
    float4 ev1 = *(const float4*)&el[(size_t)s1*4];
    float4 ev2 = *(const float4*)&el[(size_t)s2*4];
    float4 ev3 = *(const float4*)&el[(size_t)s3*4];
    const uint2* p0 = fH + (size_t)s0*128;
    const uint2* p1 = fH + (size_t)s1*128;
    const uint2* p2 = fH + (size_t)s2*128;
    const uint2* p3 = fH + (size_t)s3*128;
    uint2 a0 = p0[lane], b0 = p0[64+lane];
    uint2 a1 = p1[lane], b1 = p1[64+lane];
    uint2 a2 = p2[lane], b2 = p2[64+lane];
    uint2 a3 = p3[lane], b3 = p3[64+lane];

    float w10 = __expf(lk((hsel ? ev0.y : ev0.x) + er1, 0.2f));
    float w20 = __expf(lk((hsel ? ev0.w : ev0.z) + er2, 0.2f));
    float w11 = __expf(lk((hsel ? ev1.y : ev1.x) + er1, 0.2f));
    float w21 = __expf(lk((hsel ? ev1.w : ev1.z) + er2, 0.2f));
    float w12 = __expf(lk((hsel ? ev2.y : ev2.x) + er1, 0.2f));
    float w22 = __expf(lk((hsel ? ev2.w : ev2.z) + er2, 0.2f));
    float w13 = __expf(lk((hsel ? ev3.y : ev3.x) + er1, 0.2f));
    float w23 = __expf(lk((hsel ? ev3.w : ev3.z) + er2, 0.2f));
    z1 += w10 + w11 + w12 + w13;
    z2 += w20 + w21 + w22 + w23;

    acc[0] += w10*lo16(a0.x) + w11*lo16(a1.x) + w12*lo16(a2.x) + w13*lo16(a3.x);
    acc[1] += w10*hi16(a0.x) + w11*hi16(a1.x) + w12*hi16(a2.x) + w13*hi16(a3.x);
    acc[2] += w10*lo16(a0.y) + w11*lo16(a1.y) + w12*lo16(a2.y) + w13*lo16(a3.y);
    acc[3] += w10*hi16(a0.y) + w11*hi16(a1.y) + w12*hi16(a2.y) + w13*hi16(a3.y);
    acc[4] += w20*lo16(b0.x) + w21*lo16(b1.x) + w22*lo16(b2.x) + w23*lo16(b3.x);
    acc[5] += w20*hi16(b0.x) + w21*hi16(b1.x) + w22*hi16(b2.x) + w23*hi16(b3.x);
    acc[6] += w20*lo16(b0.y) + w21*lo16(b1.y) + w22*lo16(b2.y) + w23*lo16(b3.y);
    acc[7] += w20*hi16(b0.y) + w21*hi16(b1.y) + w22*hi16(b2.y) + w23*hi16(b3.y);
  }
  for (; i < end; ++i){
    int s = csr_src[i];
    float4 ev = *(const float4*)&el[(size_t)s*4];
    float w1 = __expf(lk((hsel ? ev.y : ev.x) + er1, 0.2f));
    float w2 = __expf(lk((hsel ? ev.w : ev.z) + er2, 0.2f));
    z1 += w1; z2 += w2;
    const uint2* fp = fH + (size_t)s*128;
    uint2 fa = fp[lane];
    uint2 fb = fp[64 + lane];
    acc[0] += w1*lo16(fa.x); acc[1] += w1*hi16(fa.x);
    acc[2] += w1*lo16(fa.y); acc[3] += w1*hi16(fa.y);
    acc[4] += w2*lo16(fb.x); acc[5] += w2*hi16(fb.x);
    acc[6] += w2*lo16(fb.y); acc[7] += w2*hi16(fb.y);
  }
  float iz1 = 1.f / fmaxf(z1, 1e-20f);
  float iz2 = 1.f / fmaxf(z2, 1e-20f);

  uint2* rp = (uint2*)(hbuf + (size_t)node*HDIM);
  uint2 r1 = rp[lane], r2 = rp[64+lane];
  const float4* bp = (const float4*)b_gat;
  float4 b1 = bp[lane], b2 = bp[64+lane];
  float o0 = lk(acc[0]*iz1+lo16(r1.x)+b1.x, 0.01f);
  float o1 = lk(acc[1]*iz1+hi16(r1.x)+b1.y, 0.01f);
  float o2 = lk(acc[2]*iz1+lo16(r1.y)+b1.z, 0.01f);
  float o3 = lk(acc[3]*iz1+hi16(r1.y)+b1.w, 0.01f);
  float o4 = lk(acc[4]*iz2+lo16(r2.x)+b2.x, 0.01f);
  float o5 = lk(acc[5]*iz2+hi16(r2.x)+b2.y, 0.01f);
  float o6 = lk(acc[6]*iz2+lo16(r2.y)+b2.z, 0.01f);
  float o7 = lk(acc[7]*iz2+hi16(r2.y)+b2.w, 0.01f);
  uint2 w1v, w2v;
  w1v.x = (unsigned)f2bf(o0) | ((unsigned)f2bf(o1) << 16);
  w1v.y = (unsigned)f2bf(o2) | ((unsigned)f2bf(o3) << 16);
  w2v.x = (unsigned)f2bf(o4) | ((unsigned)f2bf(o5) << 16);
  w2v.y = (unsigned)f2bf(o6) | ((unsigned)f2bf(o7) << 16);
  rp[lane] = w1v; rp[64+lane] = w2v;
}

// ---------------- GEMM3 (MFMA, K=512) + LayerNorm ----------------------------------------------
__global__ __launch_bounds__(256) void k_gemm3m(const unsigned short* __restrict__ h,
                                                const unsigned short* __restrict__ Wnt,
                                                const float* __restrict__ bn,
                                                const float* __restrict__ lng,
                                                const float* __restrict__ lnb,
                                                float* __restrict__ out,
                                                unsigned short* __restrict__ xb,
                                                int writeOut){
  __shared__ __attribute__((aligned(16))) char smem[2*128*136*2];
  unsigned short* sA = (unsigned short*)smem;
  unsigned short* sB = sA + 128*136;
  float* yf = (float*)smem;
  int t = threadIdx.x;
  int m0 = blockIdx.x*128;
  int lane = t & 63, w = t >> 6;
  int wm = (w & 1)*64, wn = (w >> 1)*64;
  int lrow = lane & 15, quad = lane >> 4;

  f32x4 acc[4][4];
  #pragma unroll
  for (int mt=0;mt<4;++mt)
    #pragma unroll
    for (int nt=0;nt<4;++nt) acc[mt][nt] = (f32x4){0.f,0.f,0.f,0.f};

  for (int kc2=0; kc2<4; ++kc2){
    if (kc2) __syncthreads();
    #pragma unroll
    for (int j=0;j<8;++j){
      int c = t + j*256; int r = c>>4, kc = c&15;
      uint4 v = *(const uint4*)(h + (size_t)(m0+r)*512 + kc2*128 + kc*8);
      *(uint4*)(sA + r*136 + kc*8) = v;
    }
    #pragma unroll
    for (int j=0;j<8;++j){
      int c = t + j*256; int r = c>>4, kc = c&15;
      uint4 v = *(const uint4*)(Wnt + (size_t)r*512 + kc2*128 + kc*8);
      *(uint4*)(sB + r*136 + kc*8) = v;
    }
    __syncthreads();
    #pragma unroll
    for (int kq=0;kq<4;++kq){
      int kb = kq*32 + quad*8;
      short8 af[4], bf[4];
      #pragma unroll
      for (int mt=0;mt<4;++mt) af[mt] = *(const short8*)(sA + (wm+mt*16+lrow)*136 + kb);
      #pragma unroll
      for (int nt=0;nt<4;++nt) bf[nt] = *(const short8*)(sB + (wn+nt*16+lrow)*136 + kb);
      #pragma unroll
      for (int mt=0;mt<4;++mt)
        #pragma unroll
        for (int nt=0;nt<4;++nt)
          acc[mt][nt] = __builtin_amdgcn_mfma_f32_16x16x32_bf16(af[mt], bf[nt], acc[mt][nt], 0,0,0);
    }
  }

  float bnv[4];
  #pragma unroll
  for (int nt=0;nt<4;++nt) bnv[nt] = bn[wn + nt*16 + lrow];
  __syncthreads();
  #pragma unroll
  for (int mt=0;mt<4;++mt)
    #pragma unroll
    for (int nt=0;nt<4;++nt)
      #pragma unroll
      for (int r=0;r<4;++r)
        yf[(wm+mt*16+quad*4+r)*132 + wn+nt*16+lrow] = acc[mt][nt][r] + bnv[nt];
  __syncthreads();

  float g0 = lng[lane], g1 = lng[64+lane];
  float bb0 = lnb[lane], bb1 = lnb[64+lane];
  for (int rr = w*32; rr < w*32+32; ++rr){
    float v0 = yf[rr*132 + lane], v1 = yf[rr*132 + 64 + lane];
    float s = v0 + v1;
    #pragma unroll
    for (int off=32; off>0; off>>=1) s += __shfl_xor(s, off);
    float mu = s * (1.f/128.f);
    float d0 = v0-mu, d1 = v1-mu;
    float q = d0*d0 + d1*d1;
    #pragma unroll
    for (int off=32; off>0; off>>=1) q += __shfl_xor(q, off);
    float inv = rsqrtf(q*(1.f/128.f) + 1e-5f);
    int grow = m0 + rr;
    if (grow < NN){
      float o0 = d0*inv*g0 + bb0;
      float o1 = d1*inv*g1 + bb1;
      xb[(size_t)grow*128 + lane]      = f2bf(o0);
      xb[(size_t)grow*128 + 64 + lane] = f2bf(o1);
      if (writeOut){
        out[(size_t)grow*128 + lane]      = o0;
        out[(size_t)grow*128 + 64 + lane] = o1;
      }
    }
  }
}

extern "C" void kernel_launch(void* const* d_in, const int* in_sizes, int n_in,
                              void* d_out, int out_size, void* d_ws, size_t ws_size,
                              hipStream_t stream){
  const float* features = (const float*)d_in[0];
  const int*   src      = (const int*)d_in[1];
  const int*   dst      = (const int*)d_in[2];
  const float* W_fc     = (const float*)d_in[3];
  const float* attn_l   = (const float*)d_in[4];
  const float* attn_r   = (const float*)d_in[5];
  const float* W_res    = (const float*)d_in[6];
  const float* b_gat    = (const float*)d_in[7];
  const float* W_nrm    = (const float*)d_in[8];
  const float* b_nrm    = (const float*)d_in[9];
  const float* ln_g     = (const float*)d_in[10];
  const float* ln_b     = (const float*)d_in[11];
  float* out = (float*)d_out;

  // workspace (~122 MB)
  unsigned short* xb    = (unsigned short*)d_ws;            // [NPAD,128] bf16
  unsigned short* featH = xb + (size_t)NPAD*128;            // [NPAD,512] bf16
  unsigned short* hbuf  = featH + (size_t)NPAD*512;         // [NPAD,512] bf16
  unsigned short* W2t   = hbuf + (size_t)NPAD*512;          // [L,1024,128] bf16
  unsigned short* Wnt   = W2t + (size_t)LL*1024*128;        // [L,128,512] bf16
  float* el = (float*)(Wnt + (size_t)LL*128*512);           // [N,4]
  float* er = el + (size_t)NN*4;                            // [N,4]
  int* row_ptr = (int*)(er + (size_t)NN*4);                 // N+1
  int* cursor  = row_ptr + (NN+1);                          // N
  int* csr_src = cursor + NN;                               // E

  k_cvtw2<<<dim3(16, 2, LL), 256, 0, stream>>>(W_fc, W_res, W2t);
  k_cvtwn<<<dim3(2, 8, LL), 256, 0, stream>>>(W_nrm, Wnt);
  k_cvtx<<<(NPAD*128)/256, 256, 0, stream>>>(features, xb);
  k_zero<<<(NN+255)/256, 256, 0, stream>>>(cursor, NN);
  k_hist<<<(EE+255)/256, 256, 0, stream>>>(dst, cursor);
  k_scan<<<1, 1024, 0, stream>>>(cursor, row_ptr);
  k_copy<<<(NN+255)/256, 256, 0, stream>>>(row_ptr, cursor, NN);
  k_fill<<<(EE+255)/256, 256, 0, stream>>>(src, dst, cursor, csr_src);

  for (int l=0; l<LL; ++l){
    const unsigned short* W2l = W2t + (size_t)l*1024*128;
    const unsigned short* Wnl = Wnt + (size_t)l*128*512;
    const float* al = attn_l + (size_t)l*HH*DD;
    const float* ar = attn_r + (size_t)l*HH*DD;
    const float* bg = b_gat  + (size_t)l*HDIM;
    const float* bn = b_nrm  + (size_t)l*DD;
    const float* lg = ln_g   + (size_t)l*DD;
    const float* lb = ln_b   + (size_t)l*DD;

    k_gemm1m<<<dim3(NPAD/128, 8), 256, 0, stream>>>(xb, W2l, al, ar, featH, hbuf, el, er);
    k_agg<<<NN/4, 256, 0, stream>>>(featH, hbuf, el, er, row_ptr, csr_src, bg);
    k_gemm3m<<<NPAD/128, 256, 0, stream>>>(hbuf, Wnl, bn, lg, lb, out, xb, (l==LL-1) ? 1 : 0);
  }
}